// Round 14
// baseline (818.188 us; speedup 1.0000x reference)
//
#include <hip/hip_runtime.h>
#include <hip/hip_cooperative_groups.h>
#include <math.h>

namespace cg = cooperative_groups;

#define B_ 32
#define NODES_ 512
#define IN_ 256
#define OUT_ 128
#define CAPS_ 16
#define KW_ 5
#define M_ (B_*NODES_)            // 16384
#define N_ (KW_*OUT_)             // 640
#define NCH 32                    // node chunks of 16

typedef __attribute__((ext_vector_type(8))) short short8;
typedef __attribute__((ext_vector_type(4))) float f32x4;

// ---- workspace layout (bytes) ---- (round-5 proven: 51,642,368 total)
#define Y_BOFF   0
#define L_BOFF   41943040
#define V_BOFF   42991616
#define SP_BOFF  43253760
#define BT_SZ    (N_*IN_*2)       // 327,680 bytes each

__device__ __forceinline__ float b2f(unsigned short u) {
  union { unsigned int i; float f; } c; c.i = ((unsigned int)u) << 16; return c.f;
}
__device__ __forceinline__ unsigned short f2b(float f) {
  union { float f; unsigned int i; } c; c.f = f;
  unsigned int u = c.i;
  u += 0x7fffu + ((u >> 16) & 1u);
  return (unsigned short)(u >> 16);
}
__device__ __forceinline__ void async_load16(const void* g, void* l) {
  __builtin_amdgcn_global_load_lds(
      (const __attribute__((address_space(1))) unsigned int*)g,
      (__attribute__((address_space(3))) unsigned int*)l, 16, 0, 0);
}

// ============================================================
// conv_w: split W into K-MAJOR bf16 hi/lo panels.
// ============================================================
__global__ __launch_bounds__(256) void conv_w(const float* __restrict__ W,
                                              unsigned short* __restrict__ bThi,
                                              unsigned short* __restrict__ bTlo) {
  int n = blockIdx.x;           // 0..639
  int i = threadIdx.x;          // 0..255
  int k = n >> 7, o = n & 127;
  float v = W[((size_t)k*IN_ + i)*OUT_ + o];
  unsigned short h = f2b(v);
  size_t dst = ((size_t)(i >> 3)*N_ + n)*8 + (i & 7);
  bThi[dst] = h;
  bTlo[dst] = f2b(v - b2f(h));
}

// ============================================================
// gemm_fn (R10-proven, ~11us): FULL-N blocks, coalesced reg-staged A,
// flat gload_lds B panels, split-bf16 3-pass MFMA.
// ============================================================
__global__ __launch_bounds__(512) void gemm_fn(const float* __restrict__ x,
                                               const unsigned short* __restrict__ bThi,
                                               const unsigned short* __restrict__ bTlo,
                                               float* __restrict__ y) {
  __shared__ float A_lds[8*64*4];      //  8 KB [cg][row][4f]
  __shared__ short Bh_lds[4*640*8];    // 40 KB [kg][n][8]
  __shared__ short Bl_lds[4*640*8];    // 40 KB
  const int t    = threadIdx.x;
  const int w    = t >> 6;
  const int lane = t & 63;
  const int lrow = lane & 15;
  const int lk   = lane >> 4;
  const int m0   = blockIdx.x * 64;
  const int wn0  = w * 80;
  const int arow = t >> 3;
  const int ac4  = t & 7;

  f32x4 acc[4][5];
  #pragma unroll
  for (int i=0;i<4;++i)
    #pragma unroll
    for (int j=0;j<5;++j) acc[i][j] = (f32x4){0.f,0.f,0.f,0.f};

  for (int kbi = 0; kbi < 8; ++kbi) {
    const int kb = kbi*32;
    const unsigned short* bh_src = bThi + (size_t)kbi*4*N_*8;
    const unsigned short* bl_src = bTlo + (size_t)kbi*4*N_*8;
    #pragma unroll
    for (int q=0; q<5; ++q) {
      int db = q*512 + w*64;
      async_load16(bh_src + (size_t)(db + lane)*8, &Bh_lds[db*8]);
      async_load16(bl_src + (size_t)(db + lane)*8, &Bl_lds[db*8]);
    }
    {
      float4 av = *(const float4*)(x + (size_t)(m0 + arow)*IN_ + kb + ac4*4);
      *(float4*)&A_lds[((ac4*64) + arow)*4] = av;
    }
    __syncthreads();

    short8 ah[4], al[4];
    #pragma unroll
    for (int mi=0; mi<4; ++mi) {
      int row = mi*16 + lrow;
      f32x4 a0 = *(const f32x4*)&A_lds[((2*lk  )*64 + row)*4];
      f32x4 a1 = *(const f32x4*)&A_lds[((2*lk+1)*64 + row)*4];
      #pragma unroll
      for (int j=0; j<8; ++j) {
        float f = (j < 4) ? a0[j] : a1[j-4];
        unsigned short h = f2b(f);
        ah[mi][j] = (short)h;
        al[mi][j] = (short)f2b(f - b2f(h));
      }
    }
    #pragma unroll
    for (int ni=0; ni<5; ++ni) {
      int nb = wn0 + ni*16 + lrow;
      short8 bh = *(const short8*)&Bh_lds[(lk*N_ + nb)*8];
      short8 bl = *(const short8*)&Bl_lds[(lk*N_ + nb)*8];
      #pragma unroll
      for (int mi=0; mi<4; ++mi) {
        acc[mi][ni] = __builtin_amdgcn_mfma_f32_16x16x32_bf16(bh, ah[mi], acc[mi][ni], 0, 0, 0);
        acc[mi][ni] = __builtin_amdgcn_mfma_f32_16x16x32_bf16(bh, al[mi], acc[mi][ni], 0, 0, 0);
        acc[mi][ni] = __builtin_amdgcn_mfma_f32_16x16x32_bf16(bl, ah[mi], acc[mi][ni], 0, 0, 0);
      }
    }
    __syncthreads();
  }

  #pragma unroll
  for (int mi=0; mi<4; ++mi) {
    int m = m0 + mi*16 + lrow;
    #pragma unroll
    for (int ni=0; ni<5; ++ni) {
      int nb = wn0 + ni*16 + lk*4;
      float4 o = {acc[mi][ni][0], acc[mi][ni][1], acc[mi][ni][2], acc[mi][ni][3]};
      *(float4*)(y + (size_t)m*N_ + nb) = o;
    }
  }
}

// ============================================================
// route_all: COOPERATIVE single-kernel routing. 512 blocks x 256 thr,
// 2 blocks/CU (55 KB LDS) -> all co-resident. Block bx owns batch
// b=bx>>4, chunks {2cp, 2cp+1} (cp=bx&15). 4 sweeps; logits held in
// 2 REGISTERS/thread for the whole loop; squash distributed one
// (b,c)=(b,cp) pair per block; grid.sync() replaces kernel launches.
// Phase bodies = R8-proven math (identical arithmetic).
// ============================================================
__global__ __launch_bounds__(256) void route_all(const float* __restrict__ y,
                                                 const float* __restrict__ alpha,
                                                 const float* __restrict__ contrib,
                                                 float* __restrict__ v,
                                                 float* __restrict__ s_part,
                                                 float* __restrict__ out) {
  cg::grid_group grid = cg::this_grid();
  __shared__ __align__(16) float sh_y[16*640];      // 40 KB
  __shared__ __align__(16) float sh_v[16*132];      //  8.4 KB
  __shared__ __align__(16) float sh_alpha[16*16*5]; //  5 KB
  __shared__ float sh_logit[16][16];                // cw
  __shared__ float sh_red[256];
  __shared__ float sh_ss[2];

  const int t    = threadIdx.x;
  const int bx   = blockIdx.x;    // 0..511
  const int b    = bx >> 4;       // 0..31
  const int cp   = bx & 15;       // 0..15
  const int node = t >> 4, cap = t & 15;

  // logits live in registers across all sweeps (init from contribution)
  float lreg[2];
  #pragma unroll
  for (int hh=0; hh<2; ++hh)
    lreg[hh] = contrib[(size_t)b*NODES_ + (cp*2+hh)*16 + node];

  for (int it = 0; it < 4; ++it) {
    // ---- stage v for this sweep (it>=1) ----
    if (it >= 1) {
      const float* vbase = v + (size_t)b*CAPS_*OUT_;
      #pragma unroll
      for (int q=0; q<2; ++q) {
        int flat = (t + q*256)*4;
        int c = flat >> 7, o = flat & 127;
        float4 vv = *(const float4*)(vbase + flat);
        *(float4*)&sh_v[c*132 + o] = vv;
      }
    }

    #pragma unroll
    for (int hh=0; hh<2; ++hh) {
      const int ch = cp*2 + hh;
      const int n0 = ch*16;

      // ---- stage y (async, linear dest) + alpha ----
      const float* ybase = y + ((size_t)(b*NODES_ + n0))*N_;
      #pragma unroll
      for (int q=0; q<10; ++q) {
        int d0 = q*256 + (t & ~63);
        async_load16(ybase + (size_t)(d0 + (t & 63))*4, &sh_y[d0*4]);
      }
      const float* abase = alpha + (size_t)n0*CAPS_*KW_;
      for (int i = t; i < 320; i += 256) {
        float4 av = *(const float4*)(abase + i*4);
        *(float4*)&sh_alpha[i*4] = av;
      }
      __syncthreads();   // drains async y + LDS writes

      if (it >= 1) {
        // ---- phase 1: a[node][cap] = sum_o u*v (R8 body) ----
        const float* al = &sh_alpha[(node*16+cap)*5];
        float a0=al[0],a1=al[1],a2=al[2],a3=al[3],a4=al[4];
        const float* yb = &sh_y[node*640];
        const float* vb = &sh_v[cap*132];
        float accd = 0.f;
        #pragma unroll 4
        for (int o=0; o<128; o+=4) {
          float4 y0 = *(const float4*)(yb + 0*128 + o);
          float4 y1 = *(const float4*)(yb + 1*128 + o);
          float4 y2 = *(const float4*)(yb + 2*128 + o);
          float4 y3 = *(const float4*)(yb + 3*128 + o);
          float4 y4 = *(const float4*)(yb + 4*128 + o);
          float4 vv = *(const float4*)(vb + o);
          float ux = a0*y0.x + a1*y1.x + a2*y2.x + a3*y3.x + a4*y4.x;
          float uy = a0*y0.y + a1*y1.y + a2*y2.y + a3*y3.y + a4*y4.y;
          float uz = a0*y0.z + a1*y1.z + a2*y2.z + a3*y3.z + a4*y4.z;
          float uw = a0*y0.w + a1*y1.w + a2*y2.w + a3*y3.w + a4*y4.w;
          accd += ux*vv.x + uy*vv.y + uz*vv.z + uw*vv.w;
        }
        float newl = lreg[hh] + accd;
        lreg[hh] = newl;
        // softmax over caps: lanes 0-15 of each 16-lane group = caps of one node
        float m = newl;
        m = fmaxf(m, __shfl_xor(m, 1, 64));
        m = fmaxf(m, __shfl_xor(m, 2, 64));
        m = fmaxf(m, __shfl_xor(m, 4, 64));
        m = fmaxf(m, __shfl_xor(m, 8, 64));
        float e = __expf(newl - m);
        float ssum = e;
        ssum += __shfl_xor(ssum, 1, 64);
        ssum += __shfl_xor(ssum, 2, 64);
        ssum += __shfl_xor(ssum, 4, 64);
        ssum += __shfl_xor(ssum, 8, 64);
        sh_logit[node][cap] = e / ssum;
      } else {
        sh_logit[node][cap] = 0.0625f;   // uniform 1/16
      }
      __syncthreads();

      // ---- phase 2: s_part[c][o] = sum_nd cw*u (R8 body, c fast) ----
      float* spb = s_part + ((size_t)(b*NCH + ch))*CAPS_*OUT_;
      #pragma unroll
      for (int sl=0; sl<2; ++sl) {
        int slot = t + sl*256;
        int c  = slot & 15;
        int o  = (slot >> 4) * 4;
        float4 acc = {0.f,0.f,0.f,0.f};
        #pragma unroll 4
        for (int nd=0; nd<16; ++nd) {
          const float* al2 = &sh_alpha[(nd*16+c)*5];
          float a0=al2[0],a1=al2[1],a2=al2[2],a3=al2[3],a4=al2[4];
          const float* yb2 = &sh_y[nd*640 + o];
          float4 y0 = *(const float4*)(yb2);
          float4 y1 = *(const float4*)(yb2 + 128);
          float4 y2 = *(const float4*)(yb2 + 256);
          float4 y3 = *(const float4*)(yb2 + 384);
          float4 y4 = *(const float4*)(yb2 + 512);
          float cw = sh_logit[nd][c];
          acc.x += cw*(a0*y0.x + a1*y1.x + a2*y2.x + a3*y3.x + a4*y4.x);
          acc.y += cw*(a0*y0.y + a1*y1.y + a2*y2.y + a3*y3.y + a4*y4.y);
          acc.z += cw*(a0*y0.z + a1*y1.z + a2*y2.z + a3*y3.z + a4*y4.z);
          acc.w += cw*(a0*y0.w + a1*y1.w + a2*y2.w + a3*y3.w + a4*y4.w);
        }
        *(float4*)(spb + c*OUT_ + o) = acc;
      }
      __syncthreads();   // sh_y/sh_alpha reuse by next half
    }

    __threadfence();
    grid.sync();

    // ---- squash: this block reduces (b, c=cp) ----
    {
      const int o = t & 127, h = t >> 7;
      const float* sp = s_part + ((size_t)(b*NCH + h*16)*CAPS_ + cp)*OUT_ + o;
      float part = 0.f;
      #pragma unroll
      for (int cc=0; cc<16; ++cc) part += sp[(size_t)cc*CAPS_*OUT_];
      sh_red[h*128 + o] = part;
      __syncthreads();
      float s = 0.f;
      if (t < 128) {
        s = sh_red[t] + sh_red[128 + t];
        float ss = s*s;
        #pragma unroll
        for (int off=32; off>0; off>>=1) ss += __shfl_down(ss, off, 64);
        if ((t & 63) == 0) sh_ss[t>>6] = ss;
      }
      __syncthreads();
      if (t < 128) {
        float sn = sh_ss[0] + sh_ss[1];
        float scale = (sn/(1.f+sn)) / (sqrtf(sn)+1e-8f);
        float* dst = (it==3) ? out : v;
        dst[((size_t)b*CAPS_ + cp)*OUT_ + t] = scale*s;
      }
    }
    if (it < 3) { __threadfence(); grid.sync(); }
  }
}

// ============================================================
// Fallback path (R11-proven): route_fb + squash_k multi-kernel.
// ============================================================
#define APAD 84
__global__ __launch_bounds__(256) void route_fb(const float* __restrict__ y,
                                                const float* __restrict__ alpha,
                                                const float* __restrict__ contrib,
                                                float* __restrict__ logits,
                                                const float* __restrict__ vin,
                                                float* __restrict__ s_part,
                                                int mode) {
  __shared__ __align__(16) float sh_y[16*640];
  __shared__ __align__(16) float sh_v[16*132];
  __shared__ __align__(16) float sh_alpha[16*16*5];
  __shared__ float sh_logit[16][16];

  const int t  = threadIdx.x;
  const int ch = blockIdx.x;
  const int b  = blockIdx.y;
  const int n0 = ch*16;
  const int node = t >> 4, cap = t & 15;

  const float* ybase = y + ((size_t)(b*NODES_ + n0))*N_;
  #pragma unroll
  for (int q=0; q<10; ++q) {
    int d0 = q*256 + (t & ~63);
    async_load16(ybase + (size_t)(d0 + (t & 63))*4, &sh_y[d0*4]);
  }
  const float* abase = alpha + (size_t)n0*CAPS_*KW_;
  for (int i = t; i < 320; i += 256) {
    float4 av = *(const float4*)(abase + i*4);
    *(float4*)&sh_alpha[i*4] = av;
  }
  float lreg;
  if (mode >= 1) {
    const float* vbase = vin + (size_t)b*CAPS_*OUT_;
    #pragma unroll
    for (int q=0; q<2; ++q) {
      int flat = (t + q*256)*4;
      int c = flat >> 7, o = flat & 127;
      float4 vv = *(const float4*)(vbase + flat);
      *(float4*)&sh_v[c*132 + o] = vv;
    }
    lreg = logits[((size_t)b*CAPS_ + cap)*NODES_ + n0 + node];
  } else {
    lreg = contrib[(size_t)b*NODES_ + n0 + node];
    logits[((size_t)b*CAPS_ + cap)*NODES_ + n0 + node] = lreg;
  }
  __syncthreads();

  if (mode >= 1) {
    const float* al = &sh_alpha[(node*16+cap)*5];
    float a0=al[0],a1=al[1],a2=al[2],a3=al[3],a4=al[4];
    const float* yb = &sh_y[node*640];
    const float* vb = &sh_v[cap*132];
    float accd = 0.f;
    #pragma unroll 4
    for (int o=0; o<128; o+=4) {
      float4 y0 = *(const float4*)(yb + 0*128 + o);
      float4 y1 = *(const float4*)(yb + 1*128 + o);
      float4 y2 = *(const float4*)(yb + 2*128 + o);
      float4 y3 = *(const float4*)(yb + 3*128 + o);
      float4 y4 = *(const float4*)(yb + 4*128 + o);
      float4 vv = *(const float4*)(vb + o);
      float ux = a0*y0.x + a1*y1.x + a2*y2.x + a3*y3.x + a4*y4.x;
      float uy = a0*y0.y + a1*y1.y + a2*y2.y + a3*y3.y + a4*y4.y;
      float uz = a0*y0.z + a1*y1.z + a2*y2.z + a3*y3.z + a4*y4.z;
      float uw = a0*y0.w + a1*y1.w + a2*y2.w + a3*y3.w + a4*y4.w;
      accd += ux*vv.x + uy*vv.y + uz*vv.z + uw*vv.w;
    }
    float newl = lreg + accd;
    logits[((size_t)b*CAPS_ + cap)*NODES_ + n0 + node] = newl;
    float m = newl;
    m = fmaxf(m, __shfl_xor(m, 1, 64));
    m = fmaxf(m, __shfl_xor(m, 2, 64));
    m = fmaxf(m, __shfl_xor(m, 4, 64));
    m = fmaxf(m, __shfl_xor(m, 8, 64));
    float e = __expf(newl - m);
    float ssum = e;
    ssum += __shfl_xor(ssum, 1, 64);
    ssum += __shfl_xor(ssum, 2, 64);
    ssum += __shfl_xor(ssum, 4, 64);
    ssum += __shfl_xor(ssum, 8, 64);
    sh_logit[node][cap] = e / ssum;
  } else {
    sh_logit[node][cap] = 0.0625f;
  }
  __syncthreads();

  float* spb = s_part + ((size_t)(b*NCH + ch))*CAPS_*OUT_;
  #pragma unroll
  for (int sl=0; sl<2; ++sl) {
    int slot = t + sl*256;
    int c  = slot & 15;
    int o  = (slot >> 4) * 4;
    float4 acc = {0.f,0.f,0.f,0.f};
    #pragma unroll 4
    for (int nd=0; nd<16; ++nd) {
      const float* al2 = &sh_alpha[(nd*16+c)*5];
      float a0=al2[0],a1=al2[1],a2=al2[2],a3=al2[3],a4=al2[4];
      const float* yb2 = &sh_y[nd*640 + o];
      float4 y0 = *(const float4*)(yb2);
      float4 y1 = *(const float4*)(yb2 + 128);
      float4 y2 = *(const float4*)(yb2 + 256);
      float4 y3 = *(const float4*)(yb2 + 384);
      float4 y4 = *(const float4*)(yb2 + 512);
      float cw = sh_logit[nd][c];
      acc.x += cw*(a0*y0.x + a1*y1.x + a2*y2.x + a3*y3.x + a4*y4.x);
      acc.y += cw*(a0*y0.y + a1*y1.y + a2*y2.y + a3*y3.y + a4*y4.y);
      acc.z += cw*(a0*y0.z + a1*y1.z + a2*y2.z + a3*y3.z + a4*y4.z);
      acc.w += cw*(a0*y0.w + a1*y1.w + a2*y2.w + a3*y3.w + a4*y4.w);
    }
    *(float4*)(spb + c*OUT_ + o) = acc;
  }
}

__global__ __launch_bounds__(128) void squash_k(const float* __restrict__ s_part,
                                                float* __restrict__ out) {
  const int bc = blockIdx.x;
  const int o  = threadIdx.x;
  const int b = bc >> 4, c = bc & 15;
  const float* sp = s_part + ((size_t)(b*NCH)*CAPS_ + c)*OUT_ + o;
  float s = 0.f;
  #pragma unroll
  for (int ch=0; ch<NCH; ++ch) s += sp[(size_t)ch*CAPS_*OUT_];
  float ss = s*s;
  #pragma unroll
  for (int off=32; off>0; off>>=1) ss += __shfl_down(ss, off, 64);
  __shared__ float red[2];
  if ((o & 63) == 0) red[o>>6] = ss;
  __syncthreads();
  float sn = red[0] + red[1];
  float scale = (sn/(1.f+sn)) / (sqrtf(sn)+1e-8f);
  out[(size_t)bc*OUT_ + o] = scale*s;
}

// ============================================================
extern "C" void kernel_launch(void* const* d_in, const int* in_sizes, int n_in,
                              void* d_out, int out_size, void* d_ws, size_t ws_size,
                              hipStream_t stream) {
  const float* x       = (const float*)d_in[0];
  const float* contrib = (const float*)d_in[1];
  const float* W       = (const float*)d_in[2];
  const float* alpha   = (const float*)d_in[3];
  float* out = (float*)d_out;
  char*  wsb = (char*)d_ws;

  float* y             = (float*)(wsb + Y_BOFF);
  float* logits        = (float*)(wsb + L_BOFF);
  float* v             = (float*)(wsb + V_BOFF);
  float* s_part        = (float*)(wsb + SP_BOFF);
  unsigned short* bThi = (unsigned short*)(wsb + SP_BOFF);
  unsigned short* bTlo = (unsigned short*)(wsb + SP_BOFF + BT_SZ);

  conv_w<<<N_, 256, 0, stream>>>(W, bThi, bTlo);
  gemm_fn<<<M_/64, 512, 0, stream>>>(x, bThi, bTlo, y);

  // cooperative fused routing; fallback to proven multi-kernel path
  void* kargs[] = { (void*)&y, (void*)&alpha, (void*)&contrib,
                    (void*)&v, (void*)&s_part, (void*)&out };
  hipError_t e = hipLaunchCooperativeKernel((const void*)route_all,
                                            dim3(512), dim3(256),
                                            kargs, 0, stream);
  if (e != hipSuccess) {
    route_fb<<<dim3(NCH, B_), 256, 0, stream>>>(y, alpha, contrib, logits, v, s_part, 0);
    squash_k<<<B_*CAPS_, 128, 0, stream>>>(s_part, v);
    for (int it=0; it<3; ++it) {
      route_fb<<<dim3(NCH, B_), 256, 0, stream>>>(y, alpha, contrib, logits, v, s_part, 1);
      squash_k<<<B_*CAPS_, 128, 0, stream>>>(s_part, (it==2) ? out : v);
    }
  }
}

// Round 15
// 153.285 us; speedup vs baseline: 5.3377x; 5.3377x over previous
//
#include <hip/hip_runtime.h>
#include <math.h>

#define B_ 32
#define NODES_ 512
#define IN_ 256
#define OUT_ 128
#define CAPS_ 16
#define KW_ 5
#define M_ (B_*NODES_)            // 16384
#define N_ (KW_*OUT_)             // 640
#define NCH 32                    // node chunks of 16

typedef __attribute__((ext_vector_type(8))) short short8;
typedef __attribute__((ext_vector_type(4))) float f32x4;

// ---- workspace layout (bytes) ---- (round-5 proven: 51,642,368 total)
#define Y_BOFF   0
#define L_BOFF   41943040
#define V_BOFF   42991616
#define SP_BOFF  43253760
#define BT_SZ    (N_*IN_*2)       // 327,680 bytes each

__device__ __forceinline__ float b2f(unsigned short u) {
  union { unsigned int i; float f; } c; c.i = ((unsigned int)u) << 16; return c.f;
}
// f32 -> bf16 round-to-nearest-even (finite inputs only)
__device__ __forceinline__ unsigned short f2b(float f) {
  union { float f; unsigned int i; } c; c.f = f;
  unsigned int u = c.i;
  u += 0x7fffu + ((u >> 16) & 1u);
  return (unsigned short)(u >> 16);
}
__device__ __forceinline__ void async_load16(const void* g, void* l) {
  __builtin_amdgcn_global_load_lds(
      (const __attribute__((address_space(1))) unsigned int*)g,
      (__attribute__((address_space(3))) unsigned int*)l, 16, 0, 0);
}

// ============================================================
// conv_w: split W into K-MAJOR bf16 hi/lo panels.
// ============================================================
__global__ __launch_bounds__(256) void conv_w(const float* __restrict__ W,
                                              unsigned short* __restrict__ bThi,
                                              unsigned short* __restrict__ bTlo) {
  int n = blockIdx.x;           // 0..639
  int i = threadIdx.x;          // 0..255
  int k = n >> 7, o = n & 127;
  float v = W[((size_t)k*IN_ + i)*OUT_ + o];
  unsigned short h = f2b(v);
  size_t dst = ((size_t)(i >> 3)*N_ + n)*8 + (i & 7);
  bThi[dst] = h;
  bTlo[dst] = f2b(v - b2f(h));
}

// ============================================================
// gemm_fn (R10-proven, ~11us): FULL-N blocks, coalesced reg-staged A,
// flat gload_lds B panels, split-bf16 3-pass MFMA.
// ============================================================
__global__ __launch_bounds__(512) void gemm_fn(const float* __restrict__ x,
                                               const unsigned short* __restrict__ bThi,
                                               const unsigned short* __restrict__ bTlo,
                                               float* __restrict__ y) {
  __shared__ float A_lds[8*64*4];      //  8 KB [cg][row][4f]
  __shared__ short Bh_lds[4*640*8];    // 40 KB [kg][n][8]
  __shared__ short Bl_lds[4*640*8];    // 40 KB
  const int t    = threadIdx.x;
  const int w    = t >> 6;
  const int lane = t & 63;
  const int lrow = lane & 15;
  const int lk   = lane >> 4;
  const int m0   = blockIdx.x * 64;
  const int wn0  = w * 80;
  const int arow = t >> 3;
  const int ac4  = t & 7;

  f32x4 acc[4][5];
  #pragma unroll
  for (int i=0;i<4;++i)
    #pragma unroll
    for (int j=0;j<5;++j) acc[i][j] = (f32x4){0.f,0.f,0.f,0.f};

  for (int kbi = 0; kbi < 8; ++kbi) {
    const int kb = kbi*32;
    const unsigned short* bh_src = bThi + (size_t)kbi*4*N_*8;
    const unsigned short* bl_src = bTlo + (size_t)kbi*4*N_*8;
    #pragma unroll
    for (int q=0; q<5; ++q) {
      int db = q*512 + w*64;
      async_load16(bh_src + (size_t)(db + lane)*8, &Bh_lds[db*8]);
      async_load16(bl_src + (size_t)(db + lane)*8, &Bl_lds[db*8]);
    }
    {
      float4 av = *(const float4*)(x + (size_t)(m0 + arow)*IN_ + kb + ac4*4);
      *(float4*)&A_lds[((ac4*64) + arow)*4] = av;
    }
    __syncthreads();

    short8 ah[4], al[4];
    #pragma unroll
    for (int mi=0; mi<4; ++mi) {
      int row = mi*16 + lrow;
      f32x4 a0 = *(const f32x4*)&A_lds[((2*lk  )*64 + row)*4];
      f32x4 a1 = *(const f32x4*)&A_lds[((2*lk+1)*64 + row)*4];
      #pragma unroll
      for (int j=0; j<8; ++j) {
        float f = (j < 4) ? a0[j] : a1[j-4];
        unsigned short h = f2b(f);
        ah[mi][j] = (short)h;
        al[mi][j] = (short)f2b(f - b2f(h));
      }
    }
    #pragma unroll
    for (int ni=0; ni<5; ++ni) {
      int nb = wn0 + ni*16 + lrow;
      short8 bh = *(const short8*)&Bh_lds[(lk*N_ + nb)*8];
      short8 bl = *(const short8*)&Bl_lds[(lk*N_ + nb)*8];
      #pragma unroll
      for (int mi=0; mi<4; ++mi) {
        acc[mi][ni] = __builtin_amdgcn_mfma_f32_16x16x32_bf16(bh, ah[mi], acc[mi][ni], 0, 0, 0);
        acc[mi][ni] = __builtin_amdgcn_mfma_f32_16x16x32_bf16(bh, al[mi], acc[mi][ni], 0, 0, 0);
        acc[mi][ni] = __builtin_amdgcn_mfma_f32_16x16x32_bf16(bl, ah[mi], acc[mi][ni], 0, 0, 0);
      }
    }
    __syncthreads();
  }

  #pragma unroll
  for (int mi=0; mi<4; ++mi) {
    int m = m0 + mi*16 + lrow;
    #pragma unroll
    for (int ni=0; ni<5; ++ni) {
      int nb = wn0 + ni*16 + lk*4;
      float4 o = {acc[mi][ni][0], acc[mi][ni][1], acc[mi][ni][2], acc[mi][ni][3]};
      *(float4*)(y + (size_t)m*N_ + nb) = o;
    }
  }
}

// ============================================================
// route512: one routing sweep, 16-node chunk per block, 512 THREADS
// (was 256): same 55 KB LDS -> still 2 blocks/CU, but 16 waves/CU
// instead of 8 -> double the TLP hiding the stage->sync->compute
// serialization. Phase 1: (node, cap, o-half) + shfl-pair reduce
// (R6-proven); softmax: 16-lane butterfly. Phase 2: one (c, o-quad)
// slot per thread (R8-proven body). Math identical to R9.
// ============================================================
__global__ __launch_bounds__(512) void route512(const float* __restrict__ y,
                                                const float* __restrict__ alpha,
                                                const float* __restrict__ contrib,
                                                float* __restrict__ logits,
                                                const float* __restrict__ vin,
                                                float* __restrict__ s_part,
                                                int mode) {
  __shared__ __align__(16) float sh_y[16*640];      // 40 KB [node][k*128+o]
  __shared__ __align__(16) float sh_v[16*132];      //  8.4 KB [cap][o]
  __shared__ __align__(16) float sh_alpha[16*16*5]; //  5 KB [node][cap][k]
  __shared__ float sh_logit[16][16];                // cw

  const int t  = threadIdx.x;      // 0..511
  const int ch = blockIdx.x;       // 0..31
  const int b  = blockIdx.y;       // 0..31
  const int n0 = ch*16;
  // phase-1 mapping: 32-lane group = one node; caps interleaved with o-half
  const int node1 = t >> 5;        // 0..15
  const int cap1  = (t >> 1) & 15;
  const int half  = t & 1;

  // ---- stage y: 2560 chunks, 5 per thread, wave-uniform bases ----
  const float* ybase = y + ((size_t)(b*NODES_ + n0))*N_;
  #pragma unroll
  for (int q=0; q<5; ++q) {
    int d0 = q*512 + (t & ~63);
    async_load16(ybase + (size_t)(d0 + (t & 63))*4, &sh_y[d0*4]);
  }
  // ---- stage alpha: 320 float4 ----
  const float* abase = alpha + (size_t)n0*CAPS_*KW_;
  if (t < 320) {
    float4 av = *(const float4*)(abase + t*4);
    *(float4*)&sh_alpha[t*4] = av;
  }
  float lreg = 0.f;
  if (mode >= 1) {
    // stage v: 512 float4 covers 16x128
    int flat = t*4;
    float4 vv = *(const float4*)(vin + (size_t)b*CAPS_*OUT_ + flat);
    *(float4*)&sh_v[(flat >> 7)*132 + (flat & 127)] = vv;
    lreg = logits[((size_t)b*CAPS_ + cap1)*NODES_ + n0 + node1];
  } else {
    if (t < 256) {
      int nd = t >> 4, cp = t & 15;
      logits[((size_t)b*CAPS_ + cp)*NODES_ + n0 + nd] =
          contrib[(size_t)b*NODES_ + n0 + nd];
    }
  }
  __syncthreads();   // drains async y + LDS writes

  if (mode >= 1) {
    // ---- phase 1: a[node][cap] = sum_o u*v ; two o-halves/pair ----
    const float* al = &sh_alpha[(node1*16+cap1)*5];
    float a0=al[0],a1=al[1],a2=al[2],a3=al[3],a4=al[4];
    const float* yb = &sh_y[node1*640] + half*64;
    const float* vb = &sh_v[cap1*132]  + half*64;
    float accd = 0.f;
    #pragma unroll 4
    for (int o=0; o<64; o+=4) {
      float4 y0 = *(const float4*)(yb + 0*128 + o);
      float4 y1 = *(const float4*)(yb + 1*128 + o);
      float4 y2 = *(const float4*)(yb + 2*128 + o);
      float4 y3 = *(const float4*)(yb + 3*128 + o);
      float4 y4 = *(const float4*)(yb + 4*128 + o);
      float4 vv = *(const float4*)(vb + o);
      float ux = a0*y0.x + a1*y1.x + a2*y2.x + a3*y3.x + a4*y4.x;
      float uy = a0*y0.y + a1*y1.y + a2*y2.y + a3*y3.y + a4*y4.y;
      float uz = a0*y0.z + a1*y1.z + a2*y2.z + a3*y3.z + a4*y4.z;
      float uw = a0*y0.w + a1*y1.w + a2*y2.w + a3*y3.w + a4*y4.w;
      accd += ux*vv.x + uy*vv.y + uz*vv.z + uw*vv.w;
    }
    float tot = accd + __shfl_xor(accd, 1, 64);   // join o-halves
    float newl = lreg + tot;
    if (half == 0)
      logits[((size_t)b*CAPS_ + cap1)*NODES_ + n0 + node1] = newl;
    // softmax over caps: lane bits 1..4 = cap -> butterfly masks 2,4,8,16
    float m = newl;
    m = fmaxf(m, __shfl_xor(m, 2, 64));
    m = fmaxf(m, __shfl_xor(m, 4, 64));
    m = fmaxf(m, __shfl_xor(m, 8, 64));
    m = fmaxf(m, __shfl_xor(m, 16, 64));
    float e = __expf(newl - m);
    float ssum = e;
    ssum += __shfl_xor(ssum, 2, 64);
    ssum += __shfl_xor(ssum, 4, 64);
    ssum += __shfl_xor(ssum, 8, 64);
    ssum += __shfl_xor(ssum, 16, 64);
    if (half == 0) sh_logit[node1][cap1] = e / ssum;
  } else {
    if (t < 256) sh_logit[t >> 4][t & 15] = 0.0625f;
  }
  __syncthreads();

  // ---- phase 2: one (c, o-quad) slot per thread (c fast -> broadcast) ----
  {
    int c = t & 15;
    int o = (t >> 4) * 4;   // 0..124
    float4 acc = {0.f,0.f,0.f,0.f};
    #pragma unroll 4
    for (int nd=0; nd<16; ++nd) {
      const float* al2 = &sh_alpha[(nd*16+c)*5];
      float a0=al2[0],a1=al2[1],a2=al2[2],a3=al2[3],a4=al2[4];
      const float* yb2 = &sh_y[nd*640 + o];
      float4 y0 = *(const float4*)(yb2);
      float4 y1 = *(const float4*)(yb2 + 128);
      float4 y2 = *(const float4*)(yb2 + 256);
      float4 y3 = *(const float4*)(yb2 + 384);
      float4 y4 = *(const float4*)(yb2 + 512);
      float cw = sh_logit[nd][c];
      acc.x += cw*(a0*y0.x + a1*y1.x + a2*y2.x + a3*y3.x + a4*y4.x);
      acc.y += cw*(a0*y0.y + a1*y1.y + a2*y2.y + a3*y3.y + a4*y4.y);
      acc.z += cw*(a0*y0.z + a1*y1.z + a2*y2.z + a3*y3.z + a4*y4.z);
      acc.w += cw*(a0*y0.w + a1*y1.w + a2*y2.w + a3*y3.w + a4*y4.w);
    }
    *(float4*)(s_part + ((size_t)(b*NCH + ch)*CAPS_ + c)*OUT_ + o) = acc;
  }
}

// ============================================================
// squash_k: reduce s_part over chunks, squash, write v (or out)
// ============================================================
__global__ __launch_bounds__(128) void squash_k(const float* __restrict__ s_part,
                                                float* __restrict__ out) {
  const int bc = blockIdx.x;       // b*16+c
  const int o  = threadIdx.x;      // 0..127
  const int b = bc >> 4, c = bc & 15;
  const float* sp = s_part + ((size_t)(b*NCH)*CAPS_ + c)*OUT_ + o;
  float s = 0.f;
  #pragma unroll
  for (int ch=0; ch<NCH; ++ch) s += sp[(size_t)ch*CAPS_*OUT_];
  float ss = s*s;
  #pragma unroll
  for (int off=32; off>0; off>>=1) ss += __shfl_down(ss, off, 64);
  __shared__ float red[2];
  if ((o & 63) == 0) red[o>>6] = ss;
  __syncthreads();
  float sn = red[0] + red[1];
  float scale = (sn/(1.f+sn)) / (sqrtf(sn)+1e-8f);
  out[(size_t)bc*OUT_ + o] = scale*s;
}

// ============================================================
extern "C" void kernel_launch(void* const* d_in, const int* in_sizes, int n_in,
                              void* d_out, int out_size, void* d_ws, size_t ws_size,
                              hipStream_t stream) {
  const float* x       = (const float*)d_in[0];
  const float* contrib = (const float*)d_in[1];
  const float* W       = (const float*)d_in[2];
  const float* alpha   = (const float*)d_in[3];
  float* out = (float*)d_out;
  char*  wsb = (char*)d_ws;

  float* y             = (float*)(wsb + Y_BOFF);
  float* logits        = (float*)(wsb + L_BOFF);
  float* v             = (float*)(wsb + V_BOFF);
  float* s_part        = (float*)(wsb + SP_BOFF);
  // bT hi/lo alias the s_part region (consumed before s_part first written)
  unsigned short* bThi = (unsigned short*)(wsb + SP_BOFF);
  unsigned short* bTlo = (unsigned short*)(wsb + SP_BOFF + BT_SZ);

  conv_w<<<N_, 256, 0, stream>>>(W, bThi, bTlo);
  gemm_fn<<<M_/64, 512, 0, stream>>>(x, bThi, bTlo, y);

  route512<<<dim3(NCH, B_), 512, 0, stream>>>(y, alpha, contrib, logits, v, s_part, 0);
  squash_k<<<B_*CAPS_, 128, 0, stream>>>(s_part, v);

  for (int it=0; it<3; ++it) {
    route512<<<dim3(NCH, B_), 512, 0, stream>>>(y, alpha, contrib, logits, v, s_part, 1);
    squash_k<<<B_*CAPS_, 128, 0, stream>>>(s_part, (it==2) ? out : v);
  }
}